// Round 2
// baseline (2212.581 us; speedup 1.0000x reference)
//
#include <hip/hip_runtime.h>
#include <hip/hip_bf16.h>

typedef __hip_bfloat16 bf16;

#define Bn 4
#define Dm 512
#define Hh 8
#define DH 64
#define V3 3
#define Lq 1024
#define NM (Bn*Hh*V3)   // 96 attention maps

__device__ __forceinline__ float b2f(bf16 x) { return __bfloat162float(x); }
__device__ __forceinline__ unsigned short f2bf(float x) {
    bf16 h = __float2bfloat16(x);
    return *reinterpret_cast<unsigned short*>(&h);
}

constexpr float SCALE = 0.57735026919f; // 1/sqrt(3)

// ---------------------------------------------------------------------------
// Kernel 1: projection.  Y[l,e] = sum_d W[e,d] * x[b,d,v,l], per (b,v).
// Output stored as [m][l][dd] with m=(b*H+h)*3+v, e=h*64+dd.
// grid: (L/64, D/64, B*V3), block 256. One of outF/outH is non-null.
// ---------------------------------------------------------------------------
__global__ __launch_bounds__(256) void proj_kernel(
    const float* __restrict__ x, const float* __restrict__ W,
    float* __restrict__ outF, bf16* __restrict__ outH)
{
    __shared__ float Xs[64][65];   // [d_local][l_local]
    __shared__ float Wsh[64][65];  // [e_local][d_local]
    const int l0 = blockIdx.x * 64;
    const int e0 = blockIdx.y * 64;
    const int b  = blockIdx.z / V3;
    const int v  = blockIdx.z % V3;
    const int h  = e0 >> 6;
    const int tid = threadIdx.x;
    const int tx = tid & 15, ty = tid >> 4;
    const int tx4 = tx * 4, ty4 = ty * 4;

    float acc[4][4] = {};
    for (int d0 = 0; d0 < Dm; d0 += 64) {
        #pragma unroll
        for (int i = 0; i < 16; ++i) {
            int idx = tid + i * 256;
            int r = idx >> 6, c = idx & 63;
            Xs[r][c]  = x[((size_t)(b * Dm + d0 + r) * V3 + v) * Lq + l0 + c];
            Wsh[r][c] = W[(size_t)(e0 + r) * Dm + d0 + c];
        }
        __syncthreads();
        #pragma unroll 16
        for (int kk = 0; kk < 64; ++kk) {
            float a[4], bb[4];
            #pragma unroll
            for (int i = 0; i < 4; ++i) a[i] = Xs[kk][ty4 + i];
            #pragma unroll
            for (int j = 0; j < 4; ++j) bb[j] = Wsh[tx4 + j][kk];
            #pragma unroll
            for (int i = 0; i < 4; ++i)
                #pragma unroll
                for (int j = 0; j < 4; ++j)
                    acc[i][j] = fmaf(a[i], bb[j], acc[i][j]);
        }
        __syncthreads();
    }

    const size_t obase = (size_t)((b * Hh + h) * V3 + v) * Lq;
    #pragma unroll
    for (int i = 0; i < 4; ++i) {
        int l = l0 + ty4 + i;
        size_t rowoff = (obase + l) * 64 + tx4;
        if (outF) {
            float4 f4 = make_float4(acc[i][0], acc[i][1], acc[i][2], acc[i][3]);
            *reinterpret_cast<float4*>(outF + rowoff) = f4;
        } else {
            union { unsigned short u[4]; uint2 v2; } pk;
            #pragma unroll
            for (int j = 0; j < 4; ++j) pk.u[j] = f2bf(acc[i][j]);
            *reinterpret_cast<uint2*>(outH + rowoff) = pk.v2;
        }
    }
}

// ---------------------------------------------------------------------------
// Kernel 2a: per-row softmax stats (running max + sumexp) over scaled scores.
// grid: (L/64, NM), block 64. One thread per query row.
// ---------------------------------------------------------------------------
__global__ __launch_bounds__(64) void rowstats_kernel(
    const float* __restrict__ Qf, const float* __restrict__ Kf,
    float* __restrict__ Mrow, float* __restrict__ Lrow)
{
    __shared__ float Ks[64][65];
    const int m = blockIdx.y;
    const int l = blockIdx.x * 64 + threadIdx.x;
    const float* qrow = Qf + ((size_t)m * Lq + l) * 64;
    float q[64];
    #pragma unroll
    for (int d = 0; d < 64; ++d) q[d] = qrow[d];

    float mmax = -1e30f, lsum = 0.f;
    for (int s0 = 0; s0 < Lq; s0 += 64) {
        __syncthreads();
        #pragma unroll 8
        for (int i = 0; i < 64; ++i)
            Ks[i][threadIdx.x] = Kf[((size_t)m * Lq + s0 + i) * 64 + threadIdx.x];
        __syncthreads();
        for (int ss = 0; ss < 64; ++ss) {
            float dot = 0.f;
            #pragma unroll
            for (int d = 0; d < 64; ++d) dot = fmaf(q[d], Ks[ss][d], dot);
            float sc = dot * SCALE;
            float nm = fmaxf(mmax, sc);
            lsum = lsum * __expf(mmax - nm) + __expf(sc - nm);
            mmax = nm;
        }
    }
    Mrow[(size_t)m * Lq + l] = mmax;
    Lrow[(size_t)m * Lq + l] = lsum;
}

// ---------------------------------------------------------------------------
// Kernel 2b: recompute scores, apply softmax with precomputed stats, write
// attn (fp32) into d_out.  grid: (S/64, L/64, NM), block 256.
// ---------------------------------------------------------------------------
__global__ __launch_bounds__(256) void attn_kernel(
    const float* __restrict__ Qf, const float* __restrict__ Kf,
    const float* __restrict__ Mrow, const float* __restrict__ Lrow,
    float* __restrict__ attn_out)
{
    __shared__ float Qs[64][65];   // [l][d]
    __shared__ float Ks[64][65];   // [s][d]
    const int s0 = blockIdx.x * 64;
    const int l0 = blockIdx.y * 64;
    const int m  = blockIdx.z;
    const int tid = threadIdx.x;
    const int tx = tid & 15, ty = tid >> 4;
    const int tx4 = tx * 4, ty4 = ty * 4;

    #pragma unroll
    for (int i = 0; i < 16; ++i) {
        int idx = tid + i * 256;
        int r = idx >> 6, c = idx & 63;
        Qs[r][c] = Qf[((size_t)m * Lq + l0 + r) * 64 + c];
        Ks[r][c] = Kf[((size_t)m * Lq + s0 + r) * 64 + c];
    }
    __syncthreads();

    float acc[4][4] = {};
    #pragma unroll 16
    for (int d = 0; d < 64; ++d) {
        float a[4], bb[4];
        #pragma unroll
        for (int i = 0; i < 4; ++i) a[i] = Qs[ty4 + i][d];
        #pragma unroll
        for (int j = 0; j < 4; ++j) bb[j] = Ks[tx4 + j][d];
        #pragma unroll
        for (int i = 0; i < 4; ++i)
            #pragma unroll
            for (int j = 0; j < 4; ++j)
                acc[i][j] = fmaf(a[i], bb[j], acc[i][j]);
    }

    #pragma unroll
    for (int i = 0; i < 4; ++i) {
        int l = l0 + ty4 + i;
        float mm  = Mrow[(size_t)m * Lq + l];
        float inv = 1.0f / Lrow[(size_t)m * Lq + l];
        float4 f4;
        f4.x = __expf(acc[i][0] * SCALE - mm) * inv;
        f4.y = __expf(acc[i][1] * SCALE - mm) * inv;
        f4.z = __expf(acc[i][2] * SCALE - mm) * inv;
        f4.w = __expf(acc[i][3] * SCALE - mm) * inv;
        size_t off = (size_t)m * Lq * Lq + (size_t)l * Lq + s0 + tx4;
        *reinterpret_cast<float4*>(attn_out + off) = f4;
    }
}

// ---------------------------------------------------------------------------
// Kernel 3: O[l,d] = sum_s attn[l,s] * V[s,d] per map.  grid: (L/64, NM).
// ---------------------------------------------------------------------------
__global__ __launch_bounds__(256) void pv_kernel(
    const float* __restrict__ attn, const bf16* __restrict__ Vh,
    bf16* __restrict__ Oh)
{
    __shared__ float Ps[64][65];   // [l][s]
    __shared__ float Vs[64][65];   // [s][d]
    const int l0 = blockIdx.x * 64;
    const int m  = blockIdx.y;
    const int tid = threadIdx.x;
    const int tx = tid & 15, ty = tid >> 4;
    const int tx4 = tx * 4, ty4 = ty * 4;

    float acc[4][4] = {};
    for (int s0 = 0; s0 < Lq; s0 += 64) {
        #pragma unroll
        for (int i = 0; i < 16; ++i) {
            int idx = tid + i * 256;
            int r = idx >> 6, c = idx & 63;
            Ps[r][c] = attn[(size_t)m * Lq * Lq + (size_t)(l0 + r) * Lq + s0 + c];
            Vs[r][c] = b2f(Vh[((size_t)m * Lq + s0 + r) * 64 + c]);
        }
        __syncthreads();
        #pragma unroll 16
        for (int ss = 0; ss < 64; ++ss) {
            float a[4], bb[4];
            #pragma unroll
            for (int i = 0; i < 4; ++i) a[i] = Ps[ty4 + i][ss];
            #pragma unroll
            for (int j = 0; j < 4; ++j) bb[j] = Vs[ss][tx4 + j];
            #pragma unroll
            for (int i = 0; i < 4; ++i)
                #pragma unroll
                for (int j = 0; j < 4; ++j)
                    acc[i][j] = fmaf(a[i], bb[j], acc[i][j]);
        }
        __syncthreads();
    }

    #pragma unroll
    for (int i = 0; i < 4; ++i) {
        int l = l0 + ty4 + i;
        union { unsigned short u[4]; uint2 v2; } pk;
        #pragma unroll
        for (int j = 0; j < 4; ++j) pk.u[j] = f2bf(acc[i][j]);
        *reinterpret_cast<uint2*>(Oh + ((size_t)m * Lq + l) * 64 + tx4) = pk.v2;
    }
}

// ---------------------------------------------------------------------------
// Kernel 4: out[b,e,v,l] = sum_d Wo[e,d] * O[b,l,v,d].
// grid: (L/64, D/64, B*V3), block 256.
// ---------------------------------------------------------------------------
__global__ __launch_bounds__(256) void oproj_kernel(
    const float* __restrict__ Wo, const bf16* __restrict__ Oh,
    float* __restrict__ out)
{
    __shared__ float Ws2[64][65];  // [e][d]
    __shared__ float Os[64][65];   // [l][d]
    const int l0 = blockIdx.x * 64;
    const int e0 = blockIdx.y * 64;
    const int b  = blockIdx.z / V3;
    const int v  = blockIdx.z % V3;
    const int tid = threadIdx.x;
    const int tx = tid & 15, ty = tid >> 4;
    const int tx4 = tx * 4, ty4 = ty * 4;

    float acc[4][4] = {};   // rows: e (ty), cols: l (tx)
    for (int h = 0; h < Hh; ++h) {
        #pragma unroll
        for (int i = 0; i < 16; ++i) {
            int idx = tid + i * 256;
            int r = idx >> 6, c = idx & 63;
            Ws2[r][c] = Wo[(size_t)(e0 + r) * Dm + h * 64 + c];
            Os[r][c]  = b2f(Oh[((size_t)((b * Hh + h) * V3 + v) * Lq + l0 + r) * 64 + c]);
        }
        __syncthreads();
        #pragma unroll 16
        for (int d = 0; d < 64; ++d) {
            float a[4], bb[4];
            #pragma unroll
            for (int i = 0; i < 4; ++i) a[i] = Ws2[ty4 + i][d];
            #pragma unroll
            for (int j = 0; j < 4; ++j) bb[j] = Os[tx4 + j][d];
            #pragma unroll
            for (int i = 0; i < 4; ++i)
                #pragma unroll
                for (int j = 0; j < 4; ++j)
                    acc[i][j] = fmaf(a[i], bb[j], acc[i][j]);
        }
        __syncthreads();
    }

    #pragma unroll
    for (int i = 0; i < 4; ++i) {
        int e = e0 + ty4 + i;
        float4 f4 = make_float4(acc[i][0], acc[i][1], acc[i][2], acc[i][3]);
        size_t off = ((size_t)(b * Dm + e) * V3 + v) * Lq + l0 + tx4;
        *reinterpret_cast<float4*>(out + off) = f4;
    }
}

// ---------------------------------------------------------------------------
extern "C" void kernel_launch(void* const* d_in, const int* in_sizes, int n_in,
                              void* d_out, int out_size, void* d_ws, size_t ws_size,
                              hipStream_t stream)
{
    const float* q  = (const float*)d_in[0];
    const float* k  = (const float*)d_in[1];
    const float* vv = (const float*)d_in[2];
    const float* Wq = (const float*)d_in[3];
    const float* Wk = (const float*)d_in[4];
    const float* Wv = (const float*)d_in[5];
    const float* Wo = (const float*)d_in[6];

    float* out      = (float*)d_out;
    float* attn_out = out + (size_t)Bn * Dm * V3 * Lq;   // 6,291,456 elems in

    // workspace layout (bytes):
    //   Qf fp32 : [0,        25165824)
    //   Kf fp32 : [25165824, 50331648)
    //   Vh bf16 : [50331648, 62914560)
    //   Oh bf16 : [62914560, 75497472)
    //   Mrow    : [75497472, 75890688)
    //   Lrow    : [75890688, 76283904)
    char* w = (char*)d_ws;
    float* Qf   = (float*)(w);
    float* Kf   = (float*)(w + 25165824);
    bf16*  Vh   = (bf16*) (w + 50331648);
    bf16*  Oh   = (bf16*) (w + 62914560);
    float* Mrow = (float*)(w + 75497472);
    float* Lrow = (float*)(w + 75890688);

    dim3 b256(256);
    dim3 gproj(Lq / 64, Dm / 64, Bn * V3);

    proj_kernel<<<gproj, b256, 0, stream>>>(q,  Wq, Qf, nullptr);
    proj_kernel<<<gproj, b256, 0, stream>>>(k,  Wk, Kf, nullptr);
    proj_kernel<<<gproj, b256, 0, stream>>>(vv, Wv, nullptr, Vh);

    rowstats_kernel<<<dim3(Lq / 64, NM), dim3(64), 0, stream>>>(Qf, Kf, Mrow, Lrow);

    attn_kernel<<<dim3(Lq / 64, Lq / 64, NM), b256, 0, stream>>>(Qf, Kf, Mrow, Lrow, attn_out);

    pv_kernel<<<dim3(Lq / 64, NM), b256, 0, stream>>>(attn_out, Vh, Oh);

    oproj_kernel<<<gproj, b256, 0, stream>>>(Wo, Oh, out);
}